// Round 7
// baseline (545.101 us; speedup 1.0000x reference)
//
#include <hip/hip_runtime.h>
#include <hip/hip_bf16.h>

typedef __hip_bfloat16 bf16;
typedef unsigned short ushort_t;
typedef __bf16 bf16x8 __attribute__((ext_vector_type(8)));
typedef float  f32x4  __attribute__((ext_vector_type(4)));

#define HW    4096
#define NB    8
#define KSTR  4160     // k_t token rows per batch; token 4096 = dustbin
#define PSTR  4224     // pos col stride (33*128), cols 4097..4223 zeroed
#define NTOK  32768    // NB*HW
#define QSCALE 0.0901684400557f   // (1/16) * log2(e): folds exp->exp2

__device__ __forceinline__ float lde(const void* p, size_t i, int f32f) {
    return f32f ? ((const float*)p)[i] : (float)((const bf16*)p)[i];
}
__device__ __forceinline__ ushort_t f2bu(float f){ union { __bf16 b; ushort_t u; } cv; cv.b = (__bf16)f; return cv.u; }

// ---------------------------------------------------------------------------
// dtype detector: flag=1 if inputs are float32, 0 if bf16.
// ---------------------------------------------------------------------------
__global__ void detect_kernel(const ushort_t* xb, int* flag)
{
    __shared__ int cnt;
    const int t = threadIdx.x;
    if (t == 0) cnt = 0;
    __syncthreads();
    ushort_t h = xb[2*t];
    int e = (h >> 7) & 0xFF;
    if (e >= 133) atomicAdd(&cnt, 1);
    __syncthreads();
    if (t == 0) *flag = (cnt > 8) ? 1 : 0;
}

// ---------------------------------------------------------------------------
// prep: weights/biases -> bf16/f32 ws copies; dw taps transposed; pos fixed
// rows (mesh 32/33, ones 34, zeros 35..47, dustbin col 4096, zero tail).
// ---------------------------------------------------------------------------
struct WsPtrs {
    bf16 *fw1t, *fw2t, *pwt, *pgw1t, *pgw2t, *dwt, *pos;
    float *posw, *fb1, *fb2, *pwb, *pgb1, *pgb2, *dwb;
};

__global__ __launch_bounds__(256) void prep_kernel(
    const void* fus_w1, const void* fus_w2, const void* pw_w,
    const void* pg_w1, const void* pg_w2, const void* dw_w,
    const void* fus_b1, const void* fus_b2, const void* pw_b,
    const void* pg_b1, const void* pg_b2, const void* dw_b,
    const void* dpos, WsPtrs W, const int* flag)
{
    const int f = *flag;
    const long n_w1 = 98304, n_w2 = 65536, n_pw = 65536, n_g1 = 16384, n_g2 = 4096;
    const long n_posw = 256, n_dwt = 2304;
    const long n_b = 256, n_gb1 = 128, n_gb2 = 32;
    const long n_mesh = 65536;            // rows 32/33, cols 0..4095
    const long n_pad  = 8L*14*PSTR;       // rows 34..47 (34 = ones up to col 4096)
    const long n_dust = 272;              // rows 0..33 col 4096
    const long n_zt   = 8L*34*127;        // rows 0..33 cols 4097..4223
    const long total = n_w1+n_w2+n_pw+n_g1+n_g2+n_posw+n_dwt
                     + 3*n_b + n_gb1 + n_gb2 + n_b + n_mesh + n_pad + n_dust + n_zt;

    for (long i = blockIdx.x*256L + threadIdx.x; i < total; i += gridDim.x*256L) {
        long j = i;
        if (j < n_w1) { W.fw1t[j] = __float2bfloat16(lde(fus_w1, j, f)); continue; } j -= n_w1;
        if (j < n_w2) { W.fw2t[j] = __float2bfloat16(lde(fus_w2, j, f)); continue; } j -= n_w2;
        if (j < n_pw) { W.pwt[j]  = __float2bfloat16(lde(pw_w,  j, f)); continue; } j -= n_pw;
        if (j < n_g1) { W.pgw1t[j] = __float2bfloat16(lde(pg_w1, (j>>7)*130 + 2 + (j&127), f)); continue; } j -= n_g1;
        if (j < n_g2) { W.pgw2t[j] = __float2bfloat16(lde(pg_w2, j, f)); continue; } j -= n_g2;
        if (j < n_posw) { W.posw[j] = lde(pg_w1, (j>>1)*130 + (j&1), f); continue; } j -= n_posw;
        if (j < n_dwt) { W.dwt[j] = __float2bfloat16(lde(dw_w, (j&255)*9 + (j>>8), f)); continue; } j -= n_dwt;
        if (j < n_b)   { W.fb1[j] = lde(fus_b1, j, f); continue; } j -= n_b;
        if (j < n_b)   { W.fb2[j] = lde(fus_b2, j, f); continue; } j -= n_b;
        if (j < n_b)   { W.pwb[j] = lde(pw_b, j, f); continue; } j -= n_b;
        if (j < n_gb1) { W.pgb1[j] = lde(pg_b1, j, f); continue; } j -= n_gb1;
        if (j < n_gb2) { W.pgb2[j] = lde(pg_b2, j, f); continue; } j -= n_gb2;
        if (j < n_b)   { W.dwb[j] = lde(dw_b, j, f); continue; } j -= n_b;
        if (j < n_mesh) {
            long b = j >> 13; int rr = (int)((j>>12)&1); int tok = (int)(j & 4095);
            float v = rr ? (-1.f + 2.f*(float)((tok>>6)&63)/63.f)
                         : (-1.f + 2.f*(float)(tok&63)/63.f);
            W.pos[((size_t)b*64 + 32 + rr)*PSTR + tok] = __float2bfloat16(v);
            continue;
        } j -= n_mesh;
        if (j < n_pad) {
            long b = j / (14L*PSTR); long rem = j % (14L*PSTR);
            int row = 34 + (int)(rem / PSTR); int tok = (int)(rem % PSTR);
            float v = (row == 34 && tok <= 4096) ? 1.f : 0.f;
            W.pos[((size_t)b*64 + row)*PSTR + tok] = __float2bfloat16(v);
            continue;
        } j -= n_pad;
        if (j < n_dust) {
            long b = j / 34; int ch = (int)(j % 34);
            W.pos[((size_t)b*64 + ch)*PSTR + 4096] = __float2bfloat16(lde(dpos, ch, f));
            continue;
        } j -= n_dust;
        { long b = j / (34*127); long rem = j % (34*127);
          int ch = (int)(rem / 127); int cc = (int)(rem % 127);
          W.pos[((size_t)b*64 + ch)*PSTR + 4097 + cc] = __float2bfloat16(0.f); }
    }
}

// ---------------------------------------------------------------------------
// transpose: ch-major [b][C][4096] (ext dtype) -> token-major bf16 rows of
// in_xy [32768][384] (main -> cols 0..255, feat -> cols 256..383).
// ---------------------------------------------------------------------------
__global__ __launch_bounds__(256) void transpose_kernel(
    const void* main_src, const void* feat_src, bf16* __restrict__ dst, const int* flag)
{
    __shared__ float Tt[64*65];
    const int t = threadIdx.x;
    const int p0 = blockIdx.x * 64;
    const int cht = blockIdx.y;
    const int b = blockIdx.z;
    const int f = *flag;

    const void* src; int ch0, srcC, dc0;
    if (cht < 4) { src = main_src; ch0 = cht*64; srcC = 256; dc0 = ch0; }
    else         { src = feat_src; ch0 = (cht-4)*64; srcC = 128; dc0 = 256 + (cht-4)*64; }

    const int p = t & 63, cq = t >> 6;
    #pragma unroll
    for (int e = 0; e < 16; ++e) {
        int c = e*4 + cq;
        Tt[p*65 + c] = lde(src, ((size_t)b*srcC + ch0 + c)*HW + p0 + p, f);
    }
    __syncthreads();
    const int pr = t >> 2, cs = (t & 3) * 16;
    union { uint4 u4[2]; ushort_t us[16]; } pk;
    #pragma unroll
    for (int u = 0; u < 16; ++u) pk.us[u] = f2bu(Tt[pr*65 + cs + u]);
    ushort_t* op = (ushort_t*)dst + ((size_t)b*HW + p0 + pr)*384 + dc0 + cs;
    *(uint4*)op = pk.u4[0];
    *((uint4*)op + 1) = pk.u4[1];
}

// ---------------------------------------------------------------------------
// MFMA GEMM, token-major, register-double-buffered k-loop.
// A [NTOK][sa] bf16 (k-contig), Bw [M][ldb] bf16. 128 tok x MT*16 m / block.
// OMODE 0: out[tok*sm + m]; 2: out[(tok + 64*(tok>>12))*sm + m] (k_t);
// 1: pos-mode out[((tok>>12)*64 + m)*PSTR + tok&4095].
// ---------------------------------------------------------------------------
template<int MT, bool RELU, bool POSEPI, int OMODE>
__global__ __launch_bounds__(256) void gemm_mfma(
    const bf16* __restrict__ A, int sa,
    const bf16* __restrict__ Bw, int ldb,
    const float* __restrict__ bias, const float* __restrict__ posw,
    bf16* __restrict__ out, int sm, int K, float oscale)
{
    const int t = threadIdx.x;
    const int w = t >> 6, lane = t & 63;
    const int n = lane & 15, quad = lane >> 4;
    const int p0 = blockIdx.x * 128;
    const int m0 = blockIdx.y * (MT*16);
    const int rowbase = p0 + w*32;

    f32x4 acc[2][MT];
    #pragma unroll
    for (int pt = 0; pt < 2; ++pt)
        #pragma unroll
        for (int mt = 0; mt < MT; ++mt) acc[pt][mt] = (f32x4){0.f,0.f,0.f,0.f};

    const bf16* Ar0 = A + (size_t)(rowbase + n)*sa + quad*8;
    const bf16* Ar1 = A + (size_t)(rowbase + 16 + n)*sa + quad*8;

    bf16x8 a0 = *(const bf16x8*)Ar0;
    bf16x8 a1 = *(const bf16x8*)Ar1;
    bf16x8 bw[MT];
    #pragma unroll
    for (int mt = 0; mt < MT; ++mt)
        bw[mt] = *(const bf16x8*)&Bw[(size_t)(m0 + mt*16 + n)*ldb + quad*8];

    const int kmax = K - 32;
    for (int k0 = 0; k0 < K; k0 += 32) {
        const int kn = (k0 < kmax) ? k0 + 32 : k0;
        bf16x8 na0 = *(const bf16x8*)(Ar0 + kn);
        bf16x8 na1 = *(const bf16x8*)(Ar1 + kn);
        bf16x8 nbw[MT];
        #pragma unroll
        for (int mt = 0; mt < MT; ++mt)
            nbw[mt] = *(const bf16x8*)&Bw[(size_t)(m0 + mt*16 + n)*ldb + kn + quad*8];
        #pragma unroll
        for (int mt = 0; mt < MT; ++mt) {
            acc[0][mt] = __builtin_amdgcn_mfma_f32_16x16x32_bf16(a0, bw[mt], acc[0][mt], 0, 0, 0);
            acc[1][mt] = __builtin_amdgcn_mfma_f32_16x16x32_bf16(a1, bw[mt], acc[1][mt], 0, 0, 0);
        }
        a0 = na0; a1 = na1;
        #pragma unroll
        for (int mt = 0; mt < MT; ++mt) bw[mt] = nbw[mt];
    }

    #pragma unroll
    for (int mt = 0; mt < MT; ++mt) {
        const int m = m0 + mt*16 + n;
        const float bi = bias[m];
        float w0 = 0.f, w1 = 0.f;
        if (POSEPI) { w0 = posw[m*2]; w1 = posw[m*2 + 1]; }
        #pragma unroll
        for (int pt = 0; pt < 2; ++pt) {
            const int tokb = rowbase + pt*16 + quad*4;
            if (OMODE == 1) {
                union { uint2 u2; ushort_t us[4]; } pk;
                #pragma unroll
                for (int r = 0; r < 4; ++r) {
                    float v = acc[pt][mt][r] + bi;
                    if (RELU) v = fmaxf(v, 0.f);
                    pk.us[r] = f2bu(v * oscale);
                }
                size_t oi = ((size_t)(tokb >> 12)*64 + m)*PSTR + (tokb & 4095);
                *(uint2*)((ushort_t*)out + oi) = pk.u2;
            } else {
                #pragma unroll
                for (int r = 0; r < 4; ++r) {
                    int tok = tokb + r;
                    float v = acc[pt][mt][r] + bi;
                    if (POSEPI) {
                        float gx1 = 2.f * (float)(tok & 63) / 63.f;
                        float gy1 = 2.f * (float)((tok >> 6) & 63) / 63.f;
                        v += w0*gx1 + w1*gy1;
                    }
                    if (RELU) v = fmaxf(v, 0.f);
                    v *= oscale;
                    size_t row = (OMODE == 2) ? (size_t)tok + 64*(size_t)(tok >> 12) : (size_t)tok;
                    out[row*sm + m] = __float2bfloat16(v);
                }
            }
        }
    }
}

// ---------------------------------------------------------------------------
// depthwise 3x3 SAME + bias, token-major bf16.
// ---------------------------------------------------------------------------
__global__ __launch_bounds__(256) void dw_kernel(
    const bf16* __restrict__ in, const bf16* __restrict__ dwt,
    const float* __restrict__ dwb, bf16* __restrict__ out)
{
    const int t = threadIdx.x;
    const int tok = blockIdx.x*8 + (t >> 5);
    const int c8 = (t & 31) * 8;
    const int b = tok >> 12, p = tok & 4095;
    const int i = p >> 6, j = p & 63;

    float acc[8];
    #pragma unroll
    for (int u = 0; u < 8; ++u) acc[u] = dwb[c8 + u];

    #pragma unroll
    for (int di = 0; di < 3; ++di) {
        int ii = i + di - 1;
        if (ii < 0 || ii >= 64) continue;
        #pragma unroll
        for (int dj = 0; dj < 3; ++dj) {
            int jj = j + dj - 1;
            if (jj < 0 || jj >= 64) continue;
            int tok2 = (b << 12) + ii*64 + jj;
            bf16x8 xv = *(const bf16x8*)&in[(size_t)tok2*256 + c8];
            bf16x8 wv = *(const bf16x8*)&dwt[(di*3 + dj)*256 + c8];
            #pragma unroll
            for (int u = 0; u < 8; ++u) acc[u] += (float)xv[u] * (float)wv[u];
        }
    }
    union { uint4 u4; ushort_t us[8]; } pk;
    #pragma unroll
    for (int u = 0; u < 8; ++u) pk.us[u] = f2bu(acc[u]);
    *(uint4*)((ushort_t*)out + (size_t)tok*256 + c8) = pk.u4;
}

// ---------------------------------------------------------------------------
// fill_late: k dustbin token row.
// ---------------------------------------------------------------------------
__global__ __launch_bounds__(256) void fill_late_kernel(
    const void* dvec, bf16* __restrict__ k_t, const int* flag)
{
    const int b = blockIdx.x, t = threadIdx.x;
    k_t[((size_t)b*KSTR + 4096)*256 + t] = __float2bfloat16(lde(dvec, t, *flag));
}

// ---------------------------------------------------------------------------
// MFMA flash attention v4: 4 waves, 64 q/block (all q per wave), waves split
// the k-dimension (wave w owns tokens i*128 + w*32 .. +32, i = 0..32).
// K and pos fragments read DIRECTLY from global (B-operand layout, 64B-granule
// coalesced). Zero barriers in the k-loop; P transpose is a per-wave LDS
// round-trip (stride 40 -> conflict-free b128 reads). One final barrier for
// the cross-wave pacc reduction. No-max softmax via exp2; l via ones-row 34.
// ---------------------------------------------------------------------------
__global__ __launch_bounds__(256, 2) void attn_kernel(
    const bf16* __restrict__ q_t, const bf16* __restrict__ k_t,
    const bf16* __restrict__ pos, void* outv, const int* flag)
{
    __shared__ __align__(16) float red[4*12*64*4];   // 48 KB reduction buffer
    __shared__ __align__(16) __bf16 Pb[4*64*40];     // 20 KB P tiles (per wave)

    const int t = threadIdx.x;
    const int w = t >> 6, lane = t & 63;
    const int n = lane & 15, quad = lane >> 4;
    const int qt = blockIdx.x, b = blockIdx.y;

    // Q fragments for all 64 q-rows (4 qtiles x 8 chunks) in registers
    bf16x8 aq[4][8];
    #pragma unroll
    for (int q2 = 0; q2 < 4; ++q2) {
        size_t qrow = (size_t)b*HW + qt*64 + q2*16 + n;
        #pragma unroll
        for (int c = 0; c < 8; ++c)
            aq[q2][c] = *(const bf16x8*)&q_t[qrow*256 + c*32 + quad*8];
    }

    f32x4 pacc[4][3];
    #pragma unroll
    for (int q2 = 0; q2 < 4; ++q2)
        #pragma unroll
        for (int ct = 0; ct < 3; ++ct) pacc[q2][ct] = (f32x4){0.f,0.f,0.f,0.f};

    const bf16* kb0 = k_t + (size_t)b*KSTR*256;
    const bf16* pb0 = pos + (size_t)b*64*PSTR;
    __bf16* Pw = Pb + w*64*40;

    for (int i = 0; i < 33; ++i) {
        const int base = i*128 + w*32;

        #pragma unroll
        for (int nt2 = 0; nt2 < 2; ++nt2) {
            const int kb = base + nt2*16;
            // K B-fragments direct from global (token kb+n, chunk c*32+quad*8)
            bf16x8 bk[8];
            #pragma unroll
            for (int c = 0; c < 8; ++c)
                bk[c] = *(const bf16x8*)&kb0[(size_t)(kb + n)*256 + c*32 + quad*8];
            f32x4 sacc[4];
            #pragma unroll
            for (int q2 = 0; q2 < 4; ++q2) sacc[q2] = (f32x4){0.f,0.f,0.f,0.f};
            #pragma unroll
            for (int c = 0; c < 8; ++c)
                #pragma unroll
                for (int q2 = 0; q2 < 4; ++q2)
                    sacc[q2] = __builtin_amdgcn_mfma_f32_16x16x32_bf16(aq[q2][c], bk[c], sacc[q2], 0, 0, 0);
            const bool ok = (kb + n) <= 4096;
            #pragma unroll
            for (int q2 = 0; q2 < 4; ++q2)
                #pragma unroll
                for (int r = 0; r < 4; ++r) {
                    float pv = ok ? __builtin_amdgcn_exp2f(sacc[q2][r]) : 0.f;
                    Pw[(q2*16 + quad*4 + r)*40 + nt2*16 + n] = (__bf16)pv;
                }
        }

        // pos B-fragments direct from global: pos[ch][base + quad*8 ..]
        bf16x8 bp[3];
        #pragma unroll
        for (int ct = 0; ct < 3; ++ct)
            bp[ct] = *(const bf16x8*)&pb0[(size_t)(ct*16 + n)*PSTR + base + quad*8];

        // PV: per qtile one K=32 MFMA against each ch-tile.
        // Pw write->read is same-wave: compiler inserts lgkmcnt, no barrier.
        #pragma unroll
        for (int q2 = 0; q2 < 4; ++q2) {
            bf16x8 aP = *(const bf16x8*)&Pw[(q2*16 + n)*40 + quad*8];
            #pragma unroll
            for (int ct = 0; ct < 3; ++ct)
                pacc[q2][ct] = __builtin_amdgcn_mfma_f32_16x16x32_bf16(aP, bp[ct], pacc[q2][ct], 0, 0, 0);
        }
    }

    // cross-wave reduction: all waves publish, wave w reduces qtile w
    #pragma unroll
    for (int q2 = 0; q2 < 4; ++q2)
        #pragma unroll
        for (int ct = 0; ct < 3; ++ct)
            *(f32x4*)&red[(((w*12) + q2*3 + ct)*64 + lane)*4] = pacc[q2][ct];
    __syncthreads();

    f32x4 sum[3];
    #pragma unroll
    for (int ct = 0; ct < 3; ++ct) {
        sum[ct] = (f32x4){0.f,0.f,0.f,0.f};
        #pragma unroll
        for (int w2 = 0; w2 < 4; ++w2) {
            f32x4 v = *(const f32x4*)&red[(((w2*12) + w*3 + ct)*64 + lane)*4];
            sum[ct] += v;
        }
    }
    const int f32o = *flag;
    float linv[4];
    #pragma unroll
    for (int r = 0; r < 4; ++r)
        linv[r] = 1.f / __shfl(sum[2][r], (lane & 48) | 2, 64);
    #pragma unroll
    for (int ct = 0; ct < 3; ++ct) {
        int ch = ct*16 + n;
        if (ch >= 34) continue;
        #pragma unroll
        for (int r = 0; r < 4; ++r) {
            float v = sum[ct][r] * linv[r];
            size_t oi = ((size_t)b*34 + ch)*HW + qt*64 + w*16 + quad*4 + r;
            if (f32o) ((float*)outv)[oi] = v;
            else      ((bf16*)outv)[oi]  = __float2bfloat16(v);
        }
    }
}

// ---------------------------------------------------------------------------
extern "C" void kernel_launch(void* const* d_in, const int* in_sizes, int n_in,
                              void* d_out, int out_size, void* d_ws, size_t ws_size,
                              hipStream_t stream)
{
    const void* x      = d_in[0];
    const void* y      = d_in[1];
    const void* feat1  = d_in[2];
    const void* feat2  = d_in[3];
    const void* pg_w1  = d_in[4];
    const void* pg_b1  = d_in[5];
    const void* pg_w2  = d_in[6];
    const void* pg_b2  = d_in[7];
    const void* fus_w1 = d_in[8];
    const void* fus_b1 = d_in[9];
    const void* fus_w2 = d_in[10];
    const void* fus_b2 = d_in[11];
    const void* dw_w   = d_in[12];
    const void* dw_b   = d_in[13];
    const void* pw_w   = d_in[14];
    const void* pw_b   = d_in[15];
    const void* dvec   = d_in[16];
    const void* dpos   = d_in[17];

    // ---- workspace layout (~64 MB) ----
    char* wsb = (char*)d_ws;
    int*  flag = (int*)wsb;
    size_t off = 16;
    bf16* R1   = (bf16*)(wsb + off); off += (size_t)NTOK*384*2;        // in_xy / yf / k_t (+slack)
    bf16* bufH = (bf16*)(wsb + off); off += (size_t)NTOK*256*2;        // hx / h1 / hy / dwv
    bf16* q_t  = (bf16*)(wsb + off); off += (size_t)NTOK*256*2;
    bf16* pos  = (bf16*)(wsb + off); off += (size_t)NB*64*PSTR*2;
    WsPtrs W;
    W.fw1t  = (bf16*)(wsb + off); off += 98304*2;
    W.fw2t  = (bf16*)(wsb + off); off += 65536*2;
    W.pwt   = (bf16*)(wsb + off); off += 65536*2;
    W.pgw1t = (bf16*)(wsb + off); off += 16384*2;
    W.pgw2t = (bf16*)(wsb + off); off += 4096*2;
    W.dwt   = (bf16*)(wsb + off); off += 2304*2;
    W.pos   = pos;
    W.posw  = (float*)(wsb + off); off += 256*4;
    W.fb1   = (float*)(wsb + off); off += 256*4;
    W.fb2   = (float*)(wsb + off); off += 256*4;
    W.pwb   = (float*)(wsb + off); off += 256*4;
    W.pgb1  = (float*)(wsb + off); off += 128*4;
    W.pgb2  = (float*)(wsb + off); off += 32*4;
    W.dwb   = (float*)(wsb + off); off += 256*4;

    bf16* in_xy = R1;
    bf16* yf    = R1;            // after in_xy dead
    bf16* k_t   = R1;            // after yf dead (row stride 256, KSTR rows/b)

    dim3 b256(256);

    // 0. dtype detect + weight/pos prep
    detect_kernel<<<1, 256, 0, stream>>>((const ushort_t*)x, flag);
    prep_kernel<<<1024, b256, 0, stream>>>(fus_w1, fus_w2, pw_w, pg_w1, pg_w2, dw_w,
                                           fus_b1, fus_b2, pw_b, pg_b1, pg_b2, dw_b,
                                           dpos, W, flag);
    // 1. x-phase: transpose(x,feat1) -> in_xy; F1x -> bufH; F2x -> q_t (scaled)
    transpose_kernel<<<dim3(64,6,NB), b256, 0, stream>>>(x, feat1, in_xy, flag);
    gemm_mfma<4, true, false, 0><<<dim3(256,4), b256, 0, stream>>>(
        in_xy, 384, W.fw1t, 384, W.fb1, nullptr, bufH, 256, 384, 1.f);
    gemm_mfma<4, false, false, 0><<<dim3(256,4), b256, 0, stream>>>(
        bufH, 256, W.fw2t, 256, W.fb2, nullptr, q_t, 256, 256, QSCALE);
    // 2. y-phase: transpose(y,feat2) -> in_xy
    transpose_kernel<<<dim3(64,6,NB), b256, 0, stream>>>(y, feat2, in_xy, flag);
    // 3. posgen FIRST (in_xy must be live; fuser-y L2 will clobber R1):
    //    L1 (feat2 cols of in_xy, meshgrid epilogue) -> bufH (128 cols);
    //    L2 -> pos rows 0..31
    gemm_mfma<4, true, true, 0><<<dim3(256,2), b256, 0, stream>>>(
        in_xy + 256, 384, W.pgw1t, 128, W.pgb1, W.posw, bufH, 128, 128, 1.f);
    gemm_mfma<2, true, false, 1><<<dim3(256,1), b256, 0, stream>>>(
        bufH, 128, W.pgw2t, 128, W.pgb2, nullptr, pos, 0, 128, 1.f);
    // 4. fuser-y: L1 -> bufH (clobbers h1, safe: posgen L2 done);
    //    L2 -> yf (R1, clobbers in_xy: last reader was fuser-y L1)
    gemm_mfma<4, true, false, 0><<<dim3(256,4), b256, 0, stream>>>(
        in_xy, 384, W.fw1t, 384, W.fb1, nullptr, bufH, 256, 384, 1.f);
    gemm_mfma<4, false, false, 0><<<dim3(256,4), b256, 0, stream>>>(
        bufH, 256, W.fw2t, 256, W.fb2, nullptr, yf, 256, 256, 1.f);
    // 5. depthwise: yf -> bufH (dwv)
    dw_kernel<<<dim3(4096), b256, 0, stream>>>(yf, W.dwt, W.dwb, bufH);
    // 6. k dustbin, then pointwise: bufH -> k_t (KSTR rows)
    fill_late_kernel<<<dim3(NB), b256, 0, stream>>>(dvec, k_t, flag);
    gemm_mfma<4, false, false, 2><<<dim3(256,4), b256, 0, stream>>>(
        bufH, 256, W.pwt, 256, W.pwb, nullptr, k_t, 256, 256, 1.f);
    // 7. attention
    attn_kernel<<<dim3(64,NB), b256, 0, stream>>>(q_t, k_t, pos, d_out, flag);
}